// Round 3
// baseline (332.741 us; speedup 1.0000x reference)
//
#include <hip/hip_runtime.h>

#define OUTSZ 7
#define SS 14               // sample rows/cols per box
#define NS 196              // samples per box
#define C_BAND 256
#define H_BAND 100
#define W_FULL 200
#define PLANE (2*H_BAND*W_FULL)   // 40000 floats per full channel plane
#define CCHUNK 64
#define NBOX 512
#define NC 4                // channels staged per iteration (one per wave)
#define MAXROWS 28          // max staged rows per channel (14 sample rows x lo/hi)
#define MAXSPANP 69         // max padded row segment width (floats)
#define PATCHF (MAXROWS*MAXSPANP)  // 1932 floats per channel patch
#define MAXI 31             // ceil(PATCHF/64) staging instrs per channel

typedef const __attribute__((address_space(1))) void gvoid_t;
typedef __attribute__((address_space(3))) void lvoid_t;

// Pre-pass: sort box indices by (batch, y1) -> sliding L2 working set.
__global__ __launch_bounds__(256) void sort_boxes_kernel(
    const float* __restrict__ boxes, int* __restrict__ perm)
{
    __shared__ int keys[NBOX];
    __shared__ int vals[NBOX];
    const int tid = threadIdx.x;
    for (int i = tid; i < NBOX; i += 256) {
        const int n = (int)boxes[i*5 + 0];
        const int y = (int)boxes[i*5 + 2];
        keys[i] = n * 256 + y;
        vals[i] = i;
    }
    __syncthreads();
    for (int size = 2; size <= NBOX; size <<= 1) {
        for (int stride = size >> 1; stride > 0; stride >>= 1) {
            const int i = (tid / stride) * (stride * 2) + (tid % stride);
            const int j = i + stride;
            const bool up = ((i & size) == 0);
            const int ki = keys[i], kj = keys[j];
            if ((ki > kj) == up) {
                keys[i] = kj; keys[j] = ki;
                const int v = vals[i]; vals[i] = vals[j]; vals[j] = v;
            }
            __syncthreads();
        }
    }
    for (int i = tid; i < NBOX; i += 256) perm[i] = vals[i];
}

__global__ __launch_bounds__(256) void roi_align_kernel(
    const float* __restrict__ feat,   // [4,256,200,200]
    const float* __restrict__ boxes,  // [512,5]
    const int*   __restrict__ perm,
    float* __restrict__ out)          // [512,512,7,7]
{
    __shared__ float  patch[NC][PATCHF];   // staged row segments, 4 channels
    __shared__ float4 s_w[NS];             // folded bilinear weights per sample
    __shared__ int    s_o0[NS];            // LDS float offset of (row_lo, xr)
    __shared__ int    s_o1[NS];            // LDS float offset of (row_hi, xr)
    __shared__ int    rowy[MAXROWS];       // patch row slot -> feature row

    const int b     = blockIdx.x;
    const int jj    = b & 7;               // (band*4+chunk): XCD spread
    const int chunk = jj & 3;
    const int band  = jj >> 2;
    const int k     = perm[b >> 3];
    const int tid   = threadIdx.x;

    const float bxf = boxes[k*5 + 0];
    const float x1  = boxes[k*5 + 1];
    const float y1  = boxes[k*5 + 2];
    const float x2  = boxes[k*5 + 3];
    const float y2  = boxes[k*5 + 4];
    const int   n   = (int)bxf;

    const float roi_w = fmaxf(x2 - x1, 1.0f);
    const float roi_h = fmaxf(y2 - y1, 1.0f);
    const float bin_w = roi_w / 7.0f;
    const float bin_h = roi_h / 7.0f;

    // Block-uniform span/row-range scalars (sample coords are monotone).
    const float xA = fminf(fmaxf(x1 + 0.25f*bin_w, 0.f), 199.f);
    const float xB = fminf(fmaxf(x1 + 6.75f*bin_w, 0.f), 199.f);
    const int xoff  = min((int)floorf(xA), W_FULL - 2);
    const int xbmax = min((int)floorf(xB), W_FULL - 2);
    const int spanw  = xbmax - xoff + 2;   // floats actually used per row
    const int spanwP = spanw | 1;          // odd stride: scatter LDS banks
    const float yA = fminf(fmaxf(y1 + 0.25f*bin_h, 0.f), 99.f);
    const float yB = fminf(fmaxf(y1 + 6.75f*bin_h, 0.f), 99.f);
    const int rmin   = (int)floorf(yA);
    const int rmaxr  = min((int)floorf(yB) + 1, H_BAND - 1);
    const int contig = rmaxr - rmin + 1;
    const bool layoutA = (contig <= MAXROWS);  // dense: stage contiguous row range
    const int nr = layoutA ? contig : MAXROWS;

    if (tid < NS) {
        const int sy = tid / SS;
        const int sx = tid - sy * SS;
        float y = y1 + ((float)(sy>>1) + ((float)(sy&1) + 0.5f) * 0.5f) * bin_h;
        float x = x1 + ((float)(sx>>1) + ((float)(sx&1) + 0.5f) * 0.5f) * bin_w;
        const bool valid = (y >= -1.0f) && (y <= 100.0f) &&
                           (x >= -1.0f) && (x <= 200.0f);
        y = fminf(fmaxf(y, 0.f), 99.f);
        x = fminf(fmaxf(x, 0.f), 199.f);
        const int y_lo = (int)floorf(y);
        const int x_lo = (int)floorf(x);
        const int y_hi = min(y_lo + 1, H_BAND - 1);
        const float ly = y - (float)y_lo;
        const float lx = x - (float)x_lo;
        const float hy = 1.f - ly, hx = 1.f - lx;
        const int xb = min(x_lo, W_FULL - 2);
        float w0, w1;
        if (x_lo == xb) { w0 = hx;  w1 = lx; }
        else            { w0 = 0.f; w1 = hx + lx; }   // clamp fold (lx==0)
        const float vs = valid ? 1.f : 0.f;
        const int xr = xb - xoff;
        int rs0, rs1;
        if (layoutA) { rs0 = y_lo - rmin; rs1 = y_hi - rmin; }
        else         { rs0 = 2*sy;        rs1 = 2*sy + 1;    }
        s_o0[tid] = rs0 * spanwP + xr;
        s_o1[tid] = rs1 * spanwP + xr;
        s_w[tid] = make_float4(hy*w0*vs, hy*w1*vs, ly*w0*vs, ly*w1*vs);
        if (!layoutA && sx == 0) { rowy[2*sy] = y_lo; rowy[2*sy + 1] = y_hi; }
    }
    if (layoutA && tid < nr) rowy[tid] = rmin + tid;
    __syncthreads();

    // Per-lane staging byte-offsets, fixed across channels: flat slot
    // (lane + 64*i) -> (row r, x xq) of the patch; goff = feature byte offset.
    const int lane = tid & 63;
    const int wv   = tid >> 6;
    const int M  = nr * spanwP;
    const int nI = (M + 63) >> 6;
    int goff[MAXI];
    #pragma unroll
    for (int i = 0; i < MAXI; ++i) {
        goff[i] = -1;
        if (i < nI) {
            const int slot = lane + (i << 6);
            if (slot < M) {
                const int r  = slot / spanwP;
                const int xq = slot - r * spanwP;
                if (xq < spanw)
                    goff[i] = (rowy[r] * W_FULL + xoff + xq) * 4;
            }
        }
    }

    const int c0 = chunk * CCHUNK;
    const char* fb = (const char*)(feat + (size_t)(n * C_BAND + c0) * PLANE
                                        + (size_t)band * (H_BAND * W_FULL));
    float* ob = out + ((size_t)k * (2*C_BAND) + (size_t)band * C_BAND + c0)
                    * (OUTSZ * OUTSZ);

    const size_t cstride = (size_t)PLANE * 4;       // channel byte stride
    const char* cb = fb + (size_t)wv * cstride;     // this wave's channel

    for (int it = 0; it < CCHUNK / NC; ++it) {
        // Stage channel (it*NC + wv) into patch[wv] (async, fire-and-forget).
        #pragma unroll
        for (int i = 0; i < MAXI; ++i) {
            if (i < nI) {
                if (goff[i] >= 0) {
                    __builtin_amdgcn_global_load_lds(
                        (gvoid_t*)(cb + goff[i]),
                        (lvoid_t*)(&patch[wv][i << 6]),
                        4, 0, 0);
                }
            }
        }
        __syncthreads();   // drains vmcnt -> staged data visible

        if (tid < NS) {
            const int c_sub = tid / 49;
            const int bin   = tid - c_sub * 49;
            const int ph = bin / 7;
            const int pw = bin - ph * 7;
            const float* pb = &patch[c_sub][0];
            const int s00 = (ph * 2) * SS + pw * 2;
            float acc = 0.f;
            #pragma unroll
            for (int iy = 0; iy < 2; ++iy) {
                #pragma unroll
                for (int ix = 0; ix < 2; ++ix) {
                    const int s = s00 + iy * SS + ix;
                    const float4 w = s_w[s];
                    const int o0 = s_o0[s];
                    const int o1 = s_o1[s];
                    acc += w.x * pb[o0] + w.y * pb[o0 + 1]
                         + w.z * pb[o1] + w.w * pb[o1 + 1];
                }
            }
            ob[(it * NC + c_sub) * 49 + bin] = acc * 0.25f;
        }
        __syncthreads();   // before next iter overwrites patch
        cb += (size_t)NC * cstride;
    }
}

extern "C" void kernel_launch(void* const* d_in, const int* in_sizes, int n_in,
                              void* d_out, int out_size, void* d_ws, size_t ws_size,
                              hipStream_t stream) {
    const float* feat  = (const float*)d_in[0];   // [4,256,200,200] f32
    const float* boxes = (const float*)d_in[1];   // [512,5] f32
    float* out = (float*)d_out;                   // [512,512,7,7] f32
    int* perm = (int*)d_ws;                       // 512 ints

    sort_boxes_kernel<<<1, 256, 0, stream>>>(boxes, perm);
    const int nblocks = NBOX * 2 * 4;             // 4096
    roi_align_kernel<<<nblocks, 256, 0, stream>>>(feat, boxes, perm, out);
}